// Round 19
// baseline (108.524 us; speedup 1.0000x reference)
//
#include <hip/hip_runtime.h>
#include <hip/hip_bf16.h>

// Problem constants
#define NB 32     // batch
#define NL 2048   // seq len
#define ND 1024   // DQ = DK = NH*DH
#define NHH 16    // heads
#define NDH 64    // head dim

typedef __bf16 bf16;
typedef __attribute__((ext_vector_type(4))) __bf16 bf16x4;
typedef __attribute__((ext_vector_type(8))) __bf16 bf16x8;
typedef __attribute__((ext_vector_type(4))) float f32x4;

#define SBAR __builtin_amdgcn_s_barrier()
#define WAIT_LGKM0 asm volatile("s_waitcnt lgkmcnt(0)" ::: "memory")
#define WAIT_VM0 asm volatile("s_waitcnt vmcnt(0)" ::: "memory")

// row swizzle on 16B granules, rows 0..3 (applied to GLOBAL source for DMA
// and to LDS read addresses — both-sides involution, rule #21)
#define SWZ(r) (((r) & 3) << 4)

__device__ __forceinline__ float dot4(float4 a, float4 b) {
  return a.x * b.x + a.y * b.y + a.z * b.z + a.w * b.w;
}

// ---------------------------------------------------------------------------
// K1: qs[b][o] = q[b] . Wq[o] + bq[o]      grid=1024, block=256
// ---------------------------------------------------------------------------
__global__ __launch_bounds__(256) void qs_kernel(
    const float* __restrict__ q, const float* __restrict__ Wq,
    const float* __restrict__ bq, float* __restrict__ qs) {
  int o = blockIdx.x;
  int lane = threadIdx.x & 63;
  int wv = threadIdx.x >> 6;
  const float4* wrow = reinterpret_cast<const float4*>(Wq + (size_t)o * ND) + lane * 4;
  float4 w0 = wrow[0], w1 = wrow[1], w2 = wrow[2], w3 = wrow[3];
#pragma unroll
  for (int bb = 0; bb < 8; ++bb) {
    int b = wv * 8 + bb;
    const float4* qr = reinterpret_cast<const float4*>(q + (size_t)b * ND) + lane * 4;
    float s = dot4(qr[0], w0) + dot4(qr[1], w1) + dot4(qr[2], w2) + dot4(qr[3], w3);
#pragma unroll
    for (int off = 32; off > 0; off >>= 1) s += __shfl_down(s, off, 64);
    if (lane == 0) qs[(size_t)b * ND + o] = s + bq[o];
  }
}

// ---------------------------------------------------------------------------
// K2: qt[b][n][i] = sum_d Wk[n*64+d][i] * qs[b][n*64+d]
// grid = 16n x 4ic x 4bg = 256 blocks, block=256 (strided s_qs stage).
// ---------------------------------------------------------------------------
__global__ __launch_bounds__(256) void qt_kernel(
    const float* __restrict__ Wk, const float* __restrict__ qs,
    float* __restrict__ qt) {
  int n  = blockIdx.x >> 4;
  int ic = (blockIdx.x >> 2) & 3;
  int bg = blockIdx.x & 3;
  int i = ic * 256 + threadIdx.x;
  __shared__ float s_qs[8][64];
  for (int t = threadIdx.x; t < 512; t += 256) {
    int b = t >> 6, d = t & 63;
    s_qs[b][d] = qs[(size_t)(bg * 8 + b) * ND + n * NDH + d];
  }
  __syncthreads();
  float acc[8];
#pragma unroll
  for (int b = 0; b < 8; ++b) acc[b] = 0.f;
  for (int d = 0; d < 64; ++d) {
    float w = Wk[((size_t)(n * NDH + d)) * ND + i];
#pragma unroll
    for (int b = 0; b < 8; ++b) acc[b] += w * s_qs[b][d];
  }
#pragma unroll
  for (int b = 0; b < 8; ++b)
    qt[((size_t)((bg * 8 + b) * NHH + n)) * ND + i] = acc[b];
}

// ---------------------------------------------------------------------------
// K2b: qb[b*16+n] = qs[b][n*64+:] . bk[n*64+:]    grid=2, block=256
// ---------------------------------------------------------------------------
__global__ __launch_bounds__(256) void qb_kernel(
    const float* __restrict__ qs, const float* __restrict__ bk,
    float* __restrict__ qb) {
  int t = blockIdx.x * 256 + threadIdx.x;
  if (t >= 512) return;
  int b = t >> 4, n = t & 15;
  float s = 0.f;
  for (int d = 0; d < 64; ++d)
    s += qs[(size_t)b * ND + n * NDH + d] * bk[n * NDH + d];
  qb[t] = s;
}

// ---------------------------------------------------------------------------
// K3 (FUSED v15): R17's proven 3-stage pipeline (vmcnt0 -> SBAR -> issue)
// at HALF tile (4 l, 16KB) so LDS ~70KB -> 2 desynchronized blocks/CU.
// grid = 32b x 16sl = 512 blocks, 512 threads; 32 tiles of 4 l each.
// kb: 4-deep DMA ring (4 x 16KB f32); pbuf, sP double-buffered.
// Interval t: vmcnt(0) [drains DMA(t+1)] + lgkm + SBAR, then:
//   DMA(t+2) issue | QK(t+1)->pbuf[(t+1)&1] | reduce(t) | PV(t-1).
// Identical sync ordering to the verified v13 — no new race surface.
// ---------------------------------------------------------------------------
__global__ __launch_bounds__(512, 4) void fused_kernel(
    const float* __restrict__ kin, const float* __restrict__ qt,
    const float* __restrict__ qb, float* __restrict__ attn,
    float* __restrict__ ctxp) {
  int bx = blockIdx.x;
  int b  = bx >> 4;
  int sl = bx & 15;
  int tid = threadIdx.x, lane = tid & 63, wv = tid >> 6;
  int kg = lane >> 4, ln16 = lane & 15;

  __shared__ __align__(16) float kbf[4][4][1024];    // 4 x 16KB f32 ring
  __shared__ __align__(16) float pbuf[2][8][4][20];  // [gen][wave][l][n]
  __shared__ __align__(16) float sP[2][4][20];       // [gen][l][n]

  // afrag: qt[b][n=ln16][wv*128 + mm*32 + kg*8 + 0..7]  (bf16, held; 16 VGPR)
  bf16x8 afrag[4];
  {
    const float* qrow = qt + ((size_t)(b * NHH + ln16)) * ND + wv * 128 + kg * 8;
#pragma unroll
    for (int mm = 0; mm < 4; ++mm) {
      f32x4 f0 = *reinterpret_cast<const f32x4*>(qrow + mm * 32);
      f32x4 f1 = *reinterpret_cast<const f32x4*>(qrow + mm * 32 + 4);
      bf16x8 v;
      v[0] = (bf16)f0[0]; v[1] = (bf16)f0[1]; v[2] = (bf16)f0[2]; v[3] = (bf16)f0[3];
      v[4] = (bf16)f1[0]; v[5] = (bf16)f1[1]; v[6] = (bf16)f1[2]; v[7] = (bf16)f1[3];
      afrag[mm] = v;
    }
  }

  // reduce personals (tid<64): l = tid&3, n = tid>>2
  int rl = tid & 3, rn = tid >> 2;
  float qbv = (tid < 64) ? qb[b * NHH + rn] : 0.f;

  // PV personals: nh = tid>>8 (8 heads each), ic = tid&255 (4 cols each)
  int nh = tid >> 8, ic = tid & 255;
  f32x4 ctxa[8];
#pragma unroll
  for (int r = 0; r < 8; ++r) ctxa[r] = (f32x4){0.f, 0.f, 0.f, 0.f};

  // DMA mapping: wave wv stages row wv>>1, half wv&1; 2 calls x 1KB.
  int srow = wv >> 1, shalf = wv & 1;
  int sw = SWZ(srow);
  const char* krow0 =
      (const char*)(kin + ((size_t)(b * NL + sl * 128 + srow)) * ND);

#define DMA_TILE(TT, BB)                                                    \
  {                                                                         \
    const char* gsrc = krow0 + (size_t)(TT) * 4 * 4096;                     \
    char* ldst = (char*)kbf + (BB) * 16384 + srow * 4096 + shalf * 2048;    \
    _Pragma("unroll")                                                       \
    for (int j = 0; j < 2; ++j) {                                           \
      int gb = (shalf * 2048 + j * 1024 + lane * 16) ^ sw;                  \
      __builtin_amdgcn_global_load_lds(                                     \
          (const unsigned int*)(gsrc + gb),                                 \
          (unsigned int*)(ldst + j * 1024), 16, 0, 0);                      \
    }                                                                       \
  }

  // prologue: DMA tile 0 -> ring slot 0
  DMA_TILE(0, 0)

  for (int t = -1; t <= 32; ++t) {
    WAIT_VM0;    // drains DMA(t+1) (the only outstanding generation)
    WAIT_LGKM0;  // previous interval's LDS writes visible
    SBAR;

    // issue DMA(t+2) into ring slot (t+2)&3 (in flight across interval)
    if (t + 2 <= 31) DMA_TILE(t + 2, (t + 2) & 3)

    // QK(t+1): partial logits; wave covers kc = wv*128 .. +127.
    if (t + 1 <= 31) {
      const char* kbc = (const char*)kbf + ((t + 1) & 3) * 16384;
      int arow = ln16 & 3;
      int swA = SWZ(arow);
      const char* rb = kbc + arow * 4096;
      f32x4 acc = {0.f, 0.f, 0.f, 0.f};
#pragma unroll
      for (int mm = 0; mm < 4; ++mm) {
        int kcb = (wv * 128 + mm * 32 + kg * 8) * 4;  // byte, multiple of 32
        f32x4 f0 = *reinterpret_cast<const f32x4*>(rb + (kcb ^ swA));
        f32x4 f1 = *reinterpret_cast<const f32x4*>(rb + (kcb ^ swA ^ 16));
        bf16x8 bfr;
        bfr[0] = (bf16)f0[0]; bfr[1] = (bf16)f0[1];
        bfr[2] = (bf16)f0[2]; bfr[3] = (bf16)f0[3];
        bfr[4] = (bf16)f1[0]; bfr[5] = (bf16)f1[1];
        bfr[6] = (bf16)f1[2]; bfr[7] = (bf16)f1[3];
        acc = __builtin_amdgcn_mfma_f32_16x16x32_bf16(afrag[mm], bfr, acc, 0, 0, 0);
      }
      if (ln16 < 4)
        *reinterpret_cast<f32x4*>(&pbuf[(t + 1) & 1][wv][ln16][kg * 4]) = acc;
    }

    // reduce(t): pbuf[t&1] -> sP[t&1] + attn (unnormalized)
    if (t >= 0 && t <= 31 && tid < 64) {
      float s = 0.f;
#pragma unroll
      for (int w = 0; w < 8; ++w) s += pbuf[t & 1][w][rl][rn];
      float p = __expf((s + qbv) * 0.125f);
      sP[t & 1][rl][rn] = p;
      attn[((size_t)(rn * NB + b)) * NL + sl * 128 + t * 4 + rl] = p;
    }

    // PV(t-1): one b128 k-read per l; 8 heads share it.
    if (t >= 1) {
      const char* kbc = (const char*)kbf + ((t - 1) & 3) * 16384;
      const float* sp = &sP[(t - 1) & 1][0][0];
#pragma unroll
      for (int l = 0; l < 4; ++l) {
        const char* rb = kbc + l * 4096;
        f32x4 kf = *reinterpret_cast<const f32x4*>(rb + ((ic * 16) ^ SWZ(l)));
        f32x4 p0 = *reinterpret_cast<const f32x4*>(sp + l * 20 + nh * 8);
        f32x4 p1 = *reinterpret_cast<const f32x4*>(sp + l * 20 + nh * 8 + 4);
#pragma unroll
        for (int n = 0; n < 4; ++n) {
          ctxa[n]     += p0[n] * kf;
          ctxa[4 + n] += p1[n] * kf;
        }
      }
    }
  }
#undef DMA_TILE

  // epilogue: store slab (disjoint (nh, ic) -> no combine)
#pragma unroll
  for (int n = 0; n < 8; ++n) {
    float* dst = ctxp + (((size_t)sl * NB + b) * NHH + nh * 8 + n) * ND + ic * 4;
    *reinterpret_cast<f32x4*>(dst) = ctxa[n];
  }
}

// ---------------------------------------------------------------------------
// K4: normalize attn rows (divide by row-sum), write invS. grid=512, block=256
// ---------------------------------------------------------------------------
__global__ __launch_bounds__(256) void norm_kernel(float* __restrict__ attn,
                                                   float* __restrict__ invS) {
  int row = blockIdx.x;
  float* p = attn + (size_t)row * NL;
  int tid = threadIdx.x;
  int lane = tid & 63, wv = tid >> 6;
  float v[8];
  float s = 0.f;
#pragma unroll
  for (int j = 0; j < 8; ++j) {
    v[j] = p[tid + j * 256];
    s += v[j];
  }
#pragma unroll
  for (int off = 32; off > 0; off >>= 1) s += __shfl_down(s, off, 64);
  __shared__ float ss[4];
  if (lane == 0) ss[wv] = s;
  __syncthreads();
  float inv = 1.f / (ss[0] + ss[1] + ss[2] + ss[3]);
  if (tid == 0) invS[row] = inv;
#pragma unroll
  for (int j = 0; j < 8; ++j) p[tid + j * 256] = v[j] * inv;
}

// ---------------------------------------------------------------------------
// K5: ctx = sum_sl ctxp[sl]  (16 slabs). grid=512, block=256, f32x4 each
// ---------------------------------------------------------------------------
__global__ __launch_bounds__(256) void reduce_kernel(
    const float* __restrict__ ctxp, float* __restrict__ ctx) {
  size_t e4 = ((size_t)blockIdx.x * 256 + threadIdx.x) * 4;
  f32x4 s = *reinterpret_cast<const f32x4*>(ctxp + e4);
#pragma unroll
  for (int sl = 1; sl < 16; ++sl)
    s += *reinterpret_cast<const f32x4*>(ctxp + (size_t)sl * NB * NHH * ND + e4);
  *reinterpret_cast<f32x4*>(ctx + e4) = s;
}

// ---------------------------------------------------------------------------
// K6: out[b][o] = (Wv[o].ctx[b][n]) * invS[n*32+b] + bv[o]   grid=1024
// ---------------------------------------------------------------------------
__global__ __launch_bounds__(256) void out_kernel(
    const float* __restrict__ Wv, const float* __restrict__ bv,
    const float* __restrict__ ctx, const float* __restrict__ invS,
    float* __restrict__ out) {
  int o = blockIdx.x;
  int n = o >> 6;
  int lane = threadIdx.x & 63;
  int wv = threadIdx.x >> 6;
  const float4* wrow = reinterpret_cast<const float4*>(Wv + (size_t)o * ND) + lane * 4;
  float4 w0 = wrow[0], w1 = wrow[1], w2 = wrow[2], w3 = wrow[3];
#pragma unroll
  for (int bb = 0; bb < 8; ++bb) {
    int b = wv * 8 + bb;
    const float4* cr =
        reinterpret_cast<const float4*>(ctx + ((size_t)(b * NHH + n)) * ND) + lane * 4;
    float s = dot4(cr[0], w0) + dot4(cr[1], w1) + dot4(cr[2], w2) + dot4(cr[3], w3);
#pragma unroll
    for (int off = 32; off > 0; off >>= 1) s += __shfl_down(s, off, 64);
    if (lane == 0) out[(size_t)b * ND + o] = s * invS[n * NB + b] + bv[o];
  }
}

// ---------------------------------------------------------------------------
extern "C" void kernel_launch(void* const* d_in, const int* in_sizes, int n_in,
                              void* d_out, int out_size, void* d_ws, size_t ws_size,
                              hipStream_t stream) {
  const float* q  = (const float*)d_in[0];
  const float* k  = (const float*)d_in[1];
  const float* Wq = (const float*)d_in[2];
  const float* bq = (const float*)d_in[3];
  const float* Wk = (const float*)d_in[4];
  const float* bk = (const float*)d_in[5];
  const float* Wv = (const float*)d_in[6];
  const float* bv = (const float*)d_in[7];

  float* out  = (float*)d_out;         // [32][1024]
  float* attn = out + NB * ND;         // [512][2048]  (n-major)

  // ws floats: qs 32768 | qt 524288 | qb 512 | invS 512 | ctx 524288 |
  //            ctxp 16*524288
  float* ws   = (float*)d_ws;
  float* qs   = ws;
  float* qt   = ws + 32768;
  float* qb   = qt + 524288;
  float* invS = qb + 512;
  float* ctx  = invS + 512;
  float* ctxp = ctx + 524288;

  qs_kernel<<<1024, 256, 0, stream>>>(q, Wq, bq, qs);
  qt_kernel<<<256, 256, 0, stream>>>(Wk, qs, qt);
  qb_kernel<<<2, 256, 0, stream>>>(qs, bk, qb);
  fused_kernel<<<512, 512, 0, stream>>>(k, qt, qb, attn, ctxp);
  norm_kernel<<<512, 256, 0, stream>>>(attn, invS);
  reduce_kernel<<<512, 256, 0, stream>>>(ctxp, ctx);
  out_kernel<<<1024, 256, 0, stream>>>(Wv, bv, ctx, invS, out);
}

// Round 20
// 95.326 us; speedup vs baseline: 1.1384x; 1.1384x over previous
//
#include <hip/hip_runtime.h>
#include <hip/hip_bf16.h>

// Problem constants
#define NB 32     // batch
#define NL 2048   // seq len
#define ND 1024   // DQ = DK = NH*DH
#define NHH 16    // heads
#define NDH 64    // head dim

typedef __bf16 bf16;
typedef __attribute__((ext_vector_type(4))) __bf16 bf16x4;
typedef __attribute__((ext_vector_type(8))) __bf16 bf16x8;
typedef __attribute__((ext_vector_type(4))) float f32x4;

#define SBAR __builtin_amdgcn_s_barrier()
#define WAIT_LGKM0 asm volatile("s_waitcnt lgkmcnt(0)" ::: "memory")
#define WAIT_VM0 asm volatile("s_waitcnt vmcnt(0)" ::: "memory")

// row swizzle on 16B granules, rows 0..7 (applied to GLOBAL source for DMA
// and to LDS read addresses — both-sides involution, rule #21)
#define SWZ(r) (((r) & 7) << 4)

__device__ __forceinline__ float dot4(float4 a, float4 b) {
  return a.x * b.x + a.y * b.y + a.z * b.z + a.w * b.w;
}

// ---------------------------------------------------------------------------
// K1: qs[b][o] = q[b] . Wq[o] + bq[o]      grid=1024, block=256
// ---------------------------------------------------------------------------
__global__ __launch_bounds__(256) void qs_kernel(
    const float* __restrict__ q, const float* __restrict__ Wq,
    const float* __restrict__ bq, float* __restrict__ qs) {
  int o = blockIdx.x;
  int lane = threadIdx.x & 63;
  int wv = threadIdx.x >> 6;
  const float4* wrow = reinterpret_cast<const float4*>(Wq + (size_t)o * ND) + lane * 4;
  float4 w0 = wrow[0], w1 = wrow[1], w2 = wrow[2], w3 = wrow[3];
#pragma unroll
  for (int bb = 0; bb < 8; ++bb) {
    int b = wv * 8 + bb;
    const float4* qr = reinterpret_cast<const float4*>(q + (size_t)b * ND) + lane * 4;
    float s = dot4(qr[0], w0) + dot4(qr[1], w1) + dot4(qr[2], w2) + dot4(qr[3], w3);
#pragma unroll
    for (int off = 32; off > 0; off >>= 1) s += __shfl_down(s, off, 64);
    if (lane == 0) qs[(size_t)b * ND + o] = s + bq[o];
  }
}

// ---------------------------------------------------------------------------
// K2 (+qb merged): blocks 0..255: qt[b][n][i]; blocks 256..257: qb.
// ---------------------------------------------------------------------------
__global__ __launch_bounds__(256) void qt_kernel(
    const float* __restrict__ Wk, const float* __restrict__ qs,
    float* __restrict__ qt, const float* __restrict__ bk,
    float* __restrict__ qb) {
  if (blockIdx.x >= 256) {  // qb blocks
    int t = (blockIdx.x - 256) * 256 + threadIdx.x;
    if (t < 512) {
      int b = t >> 4, n = t & 15;
      float s = 0.f;
      for (int d = 0; d < 64; ++d)
        s += qs[(size_t)b * ND + n * NDH + d] * bk[n * NDH + d];
      qb[t] = s;
    }
    return;
  }
  int n  = blockIdx.x >> 4;
  int ic = (blockIdx.x >> 2) & 3;
  int bg = blockIdx.x & 3;
  int i = ic * 256 + threadIdx.x;
  __shared__ float s_qs[8][64];
  for (int t = threadIdx.x; t < 512; t += 256) {
    int b = t >> 6, d = t & 63;
    s_qs[b][d] = qs[(size_t)(bg * 8 + b) * ND + n * NDH + d];
  }
  __syncthreads();
  float acc[8];
#pragma unroll
  for (int b = 0; b < 8; ++b) acc[b] = 0.f;
  for (int d = 0; d < 64; ++d) {
    float w = Wk[((size_t)(n * NDH + d)) * ND + i];
#pragma unroll
    for (int b = 0; b < 8; ++b) acc[b] += w * s_qs[b][d];
  }
#pragma unroll
  for (int b = 0; b < 8; ++b)
    qt[((size_t)((bg * 8 + b) * NHH + n)) * ND + i] = acc[b];
}

// ---------------------------------------------------------------------------
// K3 (FUSED v16): R17's verified 3-stage pipeline (vmcnt0 -> SBAR -> issue)
// with attn values buffered in LDS (abuf) and written once in the epilogue —
// the loop's only vmem ops are the DMA loads, so the per-interval vmcnt(0)
// drains exactly the prefetch generation (no store-ack stalls).
// grid = 32b x 8sl = 256 blocks (1/CU), 512 threads; 32 tiles of 8 l each.
// LDS: ring 4x32KB + pbuf 10.25KB + sP 1.25KB + abuf 16KB ~= 155.5KB.
// ---------------------------------------------------------------------------
__global__ __launch_bounds__(512, 4) void fused_kernel(
    const float* __restrict__ kin, const float* __restrict__ qt,
    const float* __restrict__ qb, float* __restrict__ attn,
    float* __restrict__ ctxp) {
  int bx = blockIdx.x;
  int b  = bx >> 3;
  int sl = bx & 7;
  int tid = threadIdx.x, lane = tid & 63, wv = tid >> 6;
  int kg = lane >> 4, ln16 = lane & 15;

  __shared__ __align__(16) float kbf[4][8][1024];    // 4 x 32KB f32 ring
  __shared__ __align__(16) float pbuf[2][8][8][20];  // [gen][wave][l][n]
  __shared__ __align__(16) float sP[2][8][20];       // [gen][l][n]
  __shared__ __align__(16) float abuf[32][8][16];    // [tile][l][n] attn stash

  // afrag: qt[b][n=ln16][wv*128 + mm*32 + kg*8 + 0..7]  (bf16, held; 16 VGPR)
  bf16x8 afrag[4];
  {
    const float* qrow = qt + ((size_t)(b * NHH + ln16)) * ND + wv * 128 + kg * 8;
#pragma unroll
    for (int mm = 0; mm < 4; ++mm) {
      f32x4 f0 = *reinterpret_cast<const f32x4*>(qrow + mm * 32);
      f32x4 f1 = *reinterpret_cast<const f32x4*>(qrow + mm * 32 + 4);
      bf16x8 v;
      v[0] = (bf16)f0[0]; v[1] = (bf16)f0[1]; v[2] = (bf16)f0[2]; v[3] = (bf16)f0[3];
      v[4] = (bf16)f1[0]; v[5] = (bf16)f1[1]; v[6] = (bf16)f1[2]; v[7] = (bf16)f1[3];
      afrag[mm] = v;
    }
  }

  // reduce personals (tid<128): l = tid&7, n = tid>>3
  int rl = tid & 7, rn = tid >> 3;
  float qbv = (tid < 128) ? qb[b * NHH + rn] : 0.f;

  // PV personals: nh = tid>>8 (8 heads each), ic = tid&255 (4 cols each)
  int nh = tid >> 8, ic = tid & 255;
  f32x4 ctxa[8];
#pragma unroll
  for (int r = 0; r < 8; ++r) ctxa[r] = (f32x4){0.f, 0.f, 0.f, 0.f};

  // DMA mapping: wave wv stages row wv of each 8-row tile; 4 calls x 1KB.
  int sw = SWZ(wv);
  const char* krow0 =
      (const char*)(kin + ((size_t)(b * NL + sl * 256 + wv)) * ND);

#define DMA_TILE(TT, BB)                                                    \
  {                                                                         \
    const char* gsrc = krow0 + (size_t)(TT) * 8 * 4096;                     \
    char* ldst = (char*)kbf + (BB) * 32768 + wv * 4096;                     \
    _Pragma("unroll")                                                       \
    for (int j = 0; j < 4; ++j) {                                           \
      int gb = (j * 1024 + lane * 16) ^ sw;                                 \
      __builtin_amdgcn_global_load_lds(                                     \
          (const unsigned int*)(gsrc + gb),                                 \
          (unsigned int*)(ldst + j * 1024), 16, 0, 0);                      \
    }                                                                       \
  }

  // prologue: DMA tile 0 -> ring slot 0
  DMA_TILE(0, 0)

  for (int t = -1; t <= 32; ++t) {
    WAIT_VM0;    // drains DMA(t+1) (the ONLY outstanding vmem — no stores)
    WAIT_LGKM0;  // previous interval's LDS writes visible
    SBAR;

    // issue DMA(t+2) into ring slot (t+2)&3 (in flight across interval)
    if (t + 2 <= 31) DMA_TILE(t + 2, (t + 2) & 3)

    // QK(t+1): partial logits; wave covers kc = wv*128 .. +127.
    if (t + 1 <= 31) {
      const char* kbc = (const char*)kbf + ((t + 1) & 3) * 32768;
      int arow = ln16 & 7;
      int swA = SWZ(arow);
      const char* rb = kbc + arow * 4096;
      f32x4 acc = {0.f, 0.f, 0.f, 0.f};
#pragma unroll
      for (int mm = 0; mm < 4; ++mm) {
        int kcb = (wv * 128 + mm * 32 + kg * 8) * 4;  // byte, multiple of 32
        f32x4 f0 = *reinterpret_cast<const f32x4*>(rb + (kcb ^ swA));
        f32x4 f1 = *reinterpret_cast<const f32x4*>(rb + (kcb ^ swA ^ 16));
        bf16x8 bfr;
        bfr[0] = (bf16)f0[0]; bfr[1] = (bf16)f0[1];
        bfr[2] = (bf16)f0[2]; bfr[3] = (bf16)f0[3];
        bfr[4] = (bf16)f1[0]; bfr[5] = (bf16)f1[1];
        bfr[6] = (bf16)f1[2]; bfr[7] = (bf16)f1[3];
        acc = __builtin_amdgcn_mfma_f32_16x16x32_bf16(afrag[mm], bfr, acc, 0, 0, 0);
      }
      if (ln16 < 8)
        *reinterpret_cast<f32x4*>(&pbuf[(t + 1) & 1][wv][ln16][kg * 4]) = acc;
    }

    // reduce(t): pbuf[t&1] -> sP[t&1] + abuf (attn stash, LDS only)
    if (t >= 0 && t <= 31 && tid < 128) {
      float s = 0.f;
#pragma unroll
      for (int w = 0; w < 8; ++w) s += pbuf[t & 1][w][rl][rn];
      float p = __expf((s + qbv) * 0.125f);
      sP[t & 1][rl][rn] = p;
      abuf[t][rl][rn] = p;
    }

    // PV(t-1): one b128 k-read per l; 8 heads share it.
    if (t >= 1) {
      const char* kbc = (const char*)kbf + ((t - 1) & 3) * 32768;
      const float* sp = &sP[(t - 1) & 1][0][0];
#pragma unroll
      for (int l = 0; l < 8; ++l) {
        const char* rb = kbc + l * 4096;
        f32x4 kf = *reinterpret_cast<const f32x4*>(rb + ((ic * 16) ^ SWZ(l)));
        f32x4 p0 = *reinterpret_cast<const f32x4*>(sp + l * 20 + nh * 8);
        f32x4 p1 = *reinterpret_cast<const f32x4*>(sp + l * 20 + nh * 8 + 4);
#pragma unroll
        for (int n = 0; n < 4; ++n) {
          ctxa[n]     += p0[n] * kf;
          ctxa[4 + n] += p1[n] * kf;
        }
      }
    }
  }
#undef DMA_TILE

  // epilogue 1: ctx slab (disjoint (nh, ic) -> no combine)
#pragma unroll
  for (int n = 0; n < 8; ++n) {
    float* dst = ctxp + (((size_t)sl * NB + b) * NHH + nh * 8 + n) * ND + ic * 4;
    *reinterpret_cast<f32x4*>(dst) = ctxa[n];
  }

  // epilogue 2: attn from abuf, coalesced over l. (abuf writes were fenced
  // by the t=32 interval's lgkm+barrier.)
  for (int idx = tid; idx < 4096; idx += 512) {
    int n = idx >> 8;      // 0..15
    int ll = idx & 255;    // l within this block's 256
    attn[((size_t)(n * NB + b)) * NL + sl * 256 + ll] = abuf[ll >> 3][ll & 7][n];
  }
}

// ---------------------------------------------------------------------------
// K4 (norm + reduce merged): blocks 0..511 normalize attn rows and write
// invS; blocks 512..1023 sum ctxp slabs into ctx. grid=1024, block=256.
// ---------------------------------------------------------------------------
__global__ __launch_bounds__(256) void normreduce_kernel(
    float* __restrict__ attn, float* __restrict__ invS,
    const float* __restrict__ ctxp, float* __restrict__ ctx) {
  if (blockIdx.x >= 512) {  // reduce part
    size_t e4 = ((size_t)(blockIdx.x - 512) * 256 + threadIdx.x) * 4;
    f32x4 s = *reinterpret_cast<const f32x4*>(ctxp + e4);
#pragma unroll
    for (int sl = 1; sl < 8; ++sl)
      s += *reinterpret_cast<const f32x4*>(ctxp + (size_t)sl * NB * NHH * ND + e4);
    *reinterpret_cast<f32x4*>(ctx + e4) = s;
    return;
  }
  int row = blockIdx.x;
  float* p = attn + (size_t)row * NL;
  int tid = threadIdx.x;
  int lane = tid & 63, wv = tid >> 6;
  float v[8];
  float s = 0.f;
#pragma unroll
  for (int j = 0; j < 8; ++j) {
    v[j] = p[tid + j * 256];
    s += v[j];
  }
#pragma unroll
  for (int off = 32; off > 0; off >>= 1) s += __shfl_down(s, off, 64);
  __shared__ float ss[4];
  if (lane == 0) ss[wv] = s;
  __syncthreads();
  float inv = 1.f / (ss[0] + ss[1] + ss[2] + ss[3]);
  if (tid == 0) invS[row] = inv;
#pragma unroll
  for (int j = 0; j < 8; ++j) p[tid + j * 256] = v[j] * inv;
}

// ---------------------------------------------------------------------------
// K6: out[b][o] = (Wv[o].ctx[b][n]) * invS[n*32+b] + bv[o]   grid=1024
// ---------------------------------------------------------------------------
__global__ __launch_bounds__(256) void out_kernel(
    const float* __restrict__ Wv, const float* __restrict__ bv,
    const float* __restrict__ ctx, const float* __restrict__ invS,
    float* __restrict__ out) {
  int o = blockIdx.x;
  int n = o >> 6;
  int lane = threadIdx.x & 63;
  int wv = threadIdx.x >> 6;
  const float4* wrow = reinterpret_cast<const float4*>(Wv + (size_t)o * ND) + lane * 4;
  float4 w0 = wrow[0], w1 = wrow[1], w2 = wrow[2], w3 = wrow[3];
#pragma unroll
  for (int bb = 0; bb < 8; ++bb) {
    int b = wv * 8 + bb;
    const float4* cr =
        reinterpret_cast<const float4*>(ctx + ((size_t)(b * NHH + n)) * ND) + lane * 4;
    float s = dot4(cr[0], w0) + dot4(cr[1], w1) + dot4(cr[2], w2) + dot4(cr[3], w3);
#pragma unroll
    for (int off = 32; off > 0; off >>= 1) s += __shfl_down(s, off, 64);
    if (lane == 0) out[(size_t)b * ND + o] = s * invS[n * NB + b] + bv[o];
  }
}

// ---------------------------------------------------------------------------
extern "C" void kernel_launch(void* const* d_in, const int* in_sizes, int n_in,
                              void* d_out, int out_size, void* d_ws, size_t ws_size,
                              hipStream_t stream) {
  const float* q  = (const float*)d_in[0];
  const float* k  = (const float*)d_in[1];
  const float* Wq = (const float*)d_in[2];
  const float* bq = (const float*)d_in[3];
  const float* Wk = (const float*)d_in[4];
  const float* bk = (const float*)d_in[5];
  const float* Wv = (const float*)d_in[6];
  const float* bv = (const float*)d_in[7];

  float* out  = (float*)d_out;         // [32][1024]
  float* attn = out + NB * ND;         // [512][2048]  (n-major)

  // ws floats: qs 32768 | qt 524288 | qb 512 | invS 512 | ctx 524288 |
  //            ctxp 8*524288
  float* ws   = (float*)d_ws;
  float* qs   = ws;
  float* qt   = ws + 32768;
  float* qb   = qt + 524288;
  float* invS = qb + 512;
  float* ctx  = invS + 512;
  float* ctxp = ctx + 524288;

  qs_kernel<<<1024, 256, 0, stream>>>(q, Wq, bq, qs);
  qt_kernel<<<258, 256, 0, stream>>>(Wk, qs, qt, bk, qb);
  fused_kernel<<<256, 512, 0, stream>>>(k, qt, qb, attn, ctxp);
  normreduce_kernel<<<1024, 256, 0, stream>>>(attn, invS, ctxp, ctx);
  out_kernel<<<1024, 256, 0, stream>>>(Wv, bv, ctx, invS, out);
}